// Round 6
// baseline (344.987 us; speedup 1.0000x reference)
//
#include <hip/hip_runtime.h>
#include <hip/hip_bf16.h>

#define NN 200000
#define NE 600000
#define NG 1024
#define HH 512
#define ECAP 1024

typedef short short8 __attribute__((ext_vector_type(8)));
typedef float f32x4 __attribute__((ext_vector_type(4)));
typedef float f32x2 __attribute__((ext_vector_type(2)));
typedef float f32x16 __attribute__((ext_vector_type(16)));

__device__ __forceinline__ unsigned short f2bf(float f){
  unsigned u = __float_as_uint(f);
  u += 0x7fffu + ((u >> 16) & 1u);
  return (unsigned short)(u >> 16);
}
__device__ __forceinline__ float bf2f(unsigned short h){
  return __uint_as_float(((unsigned)h) << 16);
}

// packed f32x8 -> bf16x8 (RTNE)
__device__ __forceinline__ short8 cvt8pk(float4 a, float4 b){
  union { short8 s; __hip_bfloat162 h[4]; } u;
  u.h[0] = __float22bfloat162_rn(make_float2(a.x, a.y));
  u.h[1] = __float22bfloat162_rn(make_float2(a.z, a.w));
  u.h[2] = __float22bfloat162_rn(make_float2(b.x, b.y));
  u.h[3] = __float22bfloat162_rn(make_float2(b.z, b.w));
  return u.s;
}

// f32x8 -> bf16 hi + bf16 lo (split-precision) — kgemm3 only
__device__ __forceinline__ void split8(const float* v, short8* hi, short8* lo){
  union { short8 s; __hip_bfloat162 h[4]; unsigned u[4]; } H, L;
#pragma unroll
  for (int p=0;p<4;++p){
    float a = v[2*p], b = v[2*p+1];
    H.h[p] = __float22bfloat162_rn(make_float2(a, b));
    unsigned hu = H.u[p];
    L.h[p] = __float22bfloat162_rn(make_float2(a - __uint_as_float(hu << 16),
                                               b - __uint_as_float(hu & 0xffff0000u)));
  }
  *hi = H.s; *lo = L.s;
}

// analytic gelu (GEMM epilogues only — 1M elements total)
__device__ __forceinline__ float gelu_f(float x){
  float p = __builtin_fmaf(x*x, -0.10294325f, -2.3022085f);
  float e = __builtin_amdgcn_exp2f(x * p);
  return x * __builtin_amdgcn_rcpf(1.0f + e);
}

// ---- true packed fp32 ops (VOP3P) — compiler does not reliably emit these ----
#define PKFMA(d,a,b,c) asm("v_pk_fma_f32 %0, %1, %2, %3" : "=v"(d) : "v"(a), "v"(b), "v"(c))
#define PKADD(d,a,b)   asm("v_pk_add_f32 %0, %1, %2"     : "=v"(d) : "v"(a), "v"(b))

// gelu-sum accumulate, bias folded: y = x' + b  (x' pre-scaled by 1/(2*sqrt2))
//   s = y^2 - 1; P(s) = E(x^2) with P(-1)=0;  aX += y; aP += P(s)
//   final: sum gelu = sqrt2 * aX + aP
#define G2B(xp_, b2_) { \
  f32x2 y_; PKADD(y_, xp_, b2_); \
  f32x2 s_; PKFMA(s_, y_, y_, n1); \
  f32x2 p_; PKFMA(p_, s_, K7, K6); \
  PKFMA(p_, p_, s_, K5); PKFMA(p_, p_, s_, K4); \
  PKFMA(p_, p_, s_, K3); PKFMA(p_, p_, s_, K2); \
  PKFMA(p_, p_, s_, K1); PKFMA(p_, p_, s_, K0); \
  PKADD(aX, aX, y_); PKADD(aP, aP, p_); }

// masked tail variant: invalid elements get y=0 -> s=-1 -> P=0, no contribution
#define G2BM(xp_, b2_, ok0_, ok1_) { \
  f32x2 y_; PKADD(y_, xp_, b2_); \
  y_[0] = (ok0_) ? y_[0] : 0.f; y_[1] = (ok1_) ? y_[1] : 0.f; \
  f32x2 s_; PKFMA(s_, y_, y_, n1); \
  f32x2 p_; PKFMA(p_, s_, K7, K6); \
  PKFMA(p_, p_, s_, K5); PKFMA(p_, p_, s_, K4); \
  PKFMA(p_, p_, s_, K3); PKFMA(p_, p_, s_, K2); \
  PKFMA(p_, p_, s_, K1); PKFMA(p_, p_, s_, K0); \
  PKADD(aX, aX, y_); PKADD(aP, aP, p_); }

#define COEFS \
  const float C0 = pcoef[0], C1 = pcoef[1], C2 = pcoef[2], C3 = pcoef[3]; \
  const float C4 = pcoef[4], C5 = pcoef[5], C6 = pcoef[6], C7 = pcoef[7]; \
  const f32x2 K0 = {C0,C0}, K1 = {C1,C1}, K2 = {C2,C2}, K3 = {C3,C3}; \
  const f32x2 K4 = {C4,C4}, K5 = {C5,C5}, K6 = {C6,C6}, K7 = {C7,C7}; \
  const f32x2 n1 = {-1.f,-1.f};

#define ISQ 0.35355339059327376f   // 1/(2*sqrt(2))
#define SQ2 1.41421356237309505f

// ========== kpre (unchanged from round 5) ==========
__global__ __launch_bounds__(256) void kpre(
    const float* __restrict__ nfw1, const float* __restrict__ nfb1,
    const float* __restrict__ nfg1, const float* __restrict__ nfbe1,
    const float* __restrict__ efw1, const float* __restrict__ efb1,
    const float* __restrict__ efg1, const float* __restrict__ efbe1,
    unsigned short* __restrict__ w1n48T, unsigned short* __restrict__ w1eT16,
    float* __restrict__ b1n_s, float* __restrict__ b1e_s,
    const int* __restrict__ bidx, int* __restrict__ nstart,
    int* __restrict__ cnt, float* __restrict__ pcoef,
    const float* __restrict__ nf, const float* __restrict__ dp,
    const int* __restrict__ ny, const float* __restrict__ ef,
    unsigned short* __restrict__ nf48, unsigned short* __restrict__ efb){
  const float rs = 0.99999500003750f;   // 1/sqrt(1+1e-5)
  int b = blockIdx.x, t = threadIdx.x;
  if (b < 2){
    int c = b*256 + t;
    float sc = efg1[c]*rs*ISQ;
#pragma unroll
    for (int k=0;k<16;++k) w1eT16[c*16+k] = f2bf(efw1[k*HH+c]*sc);
    b1e_s[c] = (efb1[c]*efg1[c]*rs + efbe1[c])*ISQ;
  } else if (b < 4){
    int c = (b-2)*256 + t;
    float sc = nfg1[c]*rs*ISQ;
#pragma unroll
    for (int k=0;k<48;++k)
      w1n48T[c*48+k] = (k < 41) ? f2bf(nfw1[k*HH+c]*sc) : (unsigned short)0;
    b1n_s[c] = (nfb1[c]*nfg1[c]*rs + nfbe1[c])*ISQ;
  } else if (b < 786){
    int i = (b-4)*256 + t;
    if (i < NN){
      int g0 = bidx[i];
      int g1 = (i+1 < NN) ? bidx[i+1] : NG;
      for (int g = g0+1; g <= g1; ++g) nstart[g] = i+1;
      if (i == 0) for (int g = 0; g <= g0; ++g) nstart[g] = 0;
    }
  } else if (b == 786){
    cnt[t] = 0; cnt[t+256] = 0; cnt[t+512] = 0; cnt[t+768] = 0;
    if (t == 0){
      double th[8], fj[8];
      for (int j=0;j<8;++j){
        th[j] = 3.14159265358979323846*((double)j + 0.5)/8.0;
        double cs = cos(th[j]);
        double u = 8.0*(cs + 1.0);
        double v = sqrt(u);
        fj[j] = 0.5*v*erf(v*0.70710678118654752);
      }
      double c[8];
      for (int k=0;k<8;++k){
        double sm = 0.0;
        for (int j=0;j<8;++j) sm += fj[j]*cos((double)k*th[j]);
        c[k] = 0.25*sm;
      }
      c[0] *= 0.5;
      const double T[8][8] = {
        { 1, 0,  0,  0,   0,    0,  0,  0},
        { 0, 1,  0,  0,   0,    0,  0,  0},
        {-1, 0,  2,  0,   0,    0,  0,  0},
        { 0,-3,  0,  4,   0,    0,  0,  0},
        { 1, 0, -8,  0,   8,    0,  0,  0},
        { 0, 5,  0,-20,   0,   16,  0,  0},
        {-1, 0, 18,  0, -48,    0, 32,  0},
        { 0,-7,  0, 56,   0, -112,  0, 64}};
      double m[8] = {0,0,0,0,0,0,0,0};
      for (int k=0;k<8;++k)
        for (int i=0;i<8;++i) m[i] += c[k]*T[k][i];
      double p0 = m[0]-m[1]+m[2]-m[3]+m[4]-m[5]+m[6]-m[7];
      m[0] -= p0;
      for (int i=0;i<8;++i) pcoef[i] = (float)m[i];
    }
  } else if (b < 1569){
    int r = (b-787)*256 + t;
    if (r < NN){
      const float4* ap = (const float4*)(nf + (size_t)r*32);
      unsigned short v[48];
      union { short8 s; unsigned short u[8]; } cv;
#pragma unroll
      for (int p2=0; p2<4; ++p2){
        cv.s = cvt8pk(ap[2*p2], ap[2*p2+1]);
#pragma unroll
        for (int j=0;j<8;++j) v[p2*8+j] = cv.u[j];
      }
      unsigned short db = f2bf(dp[r]);
      int cls = ny[r];
#pragma unroll
      for (int j=0;j<9;++j) v[32+j] = (cls==j) ? db : (unsigned short)0;
#pragma unroll
      for (int j=41;j<48;++j) v[j] = 0;
      unsigned short* op = nf48 + (size_t)r*48;
#pragma unroll
      for (int p2=0; p2<6; ++p2) *(short8*)(op + p2*8) = *(short8*)&v[p2*8];
    }
  } else {
    int r = (b-1569)*256 + t;
    if (r < NE){
      const float4* ap = (const float4*)(ef + (size_t)r*16);
      unsigned short* op = efb + (size_t)r*16;
      *(short8*)op       = cvt8pk(ap[0], ap[1]);
      *(short8*)(op + 8) = cvt8pk(ap[2], ap[3]);
    }
  }
}

// ========== kscatter: two-level scatter (unchanged) ==========
__global__ __launch_bounds__(1024) void kscatter(const int* __restrict__ eidx,
    const int* __restrict__ bidx, int* __restrict__ eg,
    int* __restrict__ cnt, int* __restrict__ perm2d){
  __shared__ int h[NG];
  __shared__ int base[NG];
  const int b = blockIdx.x, t = threadIdx.x;
  h[t] = 0;
  __syncthreads();
  const int per = NE / 64;            // 9375, exact
  const int lo = b*per, hi = lo + per;
  for (int e = lo + t; e < hi; e += 1024){
    int g = bidx[eidx[e]];
    eg[e] = g;
    atomicAdd(&h[g], 1);
  }
  __syncthreads();
  int c = h[t];
  if (c > 0) base[t] = atomicAdd(&cnt[t], c);
  h[t] = 0;
  __syncthreads();
  for (int e = lo + t; e < hi; e += 1024){
    int g = eg[e];
    int p = base[g] + atomicAdd(&h[g], 1);
    if (p < ECAP) perm2d[(g << 10) + p] = e;
  }
}

// ========== kedge: 1 block/graph, 8 waves x 64 cols, direct gather, pk-gelu ==========
__global__ __launch_bounds__(512) void kedge(
    const unsigned short* __restrict__ efb, const int* __restrict__ perm2d,
    const int* __restrict__ cnt, const unsigned short* __restrict__ w1eT16,
    const float* __restrict__ b1e_s, const float* __restrict__ pcoef,
    float* __restrict__ S){
  const int t = threadIdx.x;
  const int lane = t & 63, wid = t >> 6;
  const int hi = lane >> 5;
  const int g = blockIdx.x;
  const int col = (wid << 6) + (lane & 31);       // group0 col; group1 = col+32
  COEFS;
  short8 bfr0 = *(const short8*)(w1eT16 + col*16 + (hi<<3));
  short8 bfr1 = *(const short8*)(w1eT16 + (col+32)*16 + (hi<<3));
  float bv0 = b1e_s[col], bv1 = b1e_s[col+32];
  const f32x2 b20 = {bv0,bv0}, b21 = {bv1,bv1};
  f32x16 z16;
#pragma unroll
  for (int i=0;i<16;++i) z16[i] = 0.f;
  f32x2 aX = {0.f,0.f}, aP = {0.f,0.f};
  f32x2 aX1 = {0.f,0.f}, aP1 = {0.f,0.f};
  const int s1 = min(cnt[g], ECAP);
  const int base = g << 10;
  const int nch = (s1 + 31) >> 5;
  for (int ch=0; ch<nch; ++ch){
    const int rb = ch*32;
    int e = perm2d[base + min(rb + (lane & 31), s1-1)];
    short8 af = *(const short8*)(efb + (size_t)e*16 + (hi<<3));
    f32x16 acc0 = __builtin_amdgcn_mfma_f32_32x32x16_bf16(af, bfr0, z16, 0, 0, 0);
    f32x16 acc1 = __builtin_amdgcn_mfma_f32_32x32x16_bf16(af, bfr1, z16, 0, 0, 0);
    const int vr = s1 - rb;
    if (vr >= 32){
#pragma unroll
      for (int i=0;i<8;++i){
        f32x2 xp = {acc0[2*i], acc0[2*i+1]};
        G2B(xp, b20);
      }
#pragma unroll
      for (int i=0;i<8;++i){
        f32x2 xp = {acc1[2*i], acc1[2*i+1]};
        { f32x2 y_; PKADD(y_, xp, b21);
          f32x2 s_; PKFMA(s_, y_, y_, n1);
          f32x2 p_; PKFMA(p_, s_, K7, K6);
          PKFMA(p_, p_, s_, K5); PKFMA(p_, p_, s_, K4);
          PKFMA(p_, p_, s_, K3); PKFMA(p_, p_, s_, K2);
          PKFMA(p_, p_, s_, K1); PKFMA(p_, p_, s_, K0);
          PKADD(aX1, aX1, y_); PKADD(aP1, aP1, p_); }
      }
    } else {
#pragma unroll
      for (int i=0;i<8;++i){
        int r0 = ((2*i)&3) + (((2*i)>>2)<<3) + (hi<<2);
        bool ok0 = r0 < vr, ok1 = (r0+1) < vr;
        f32x2 xp = {acc0[2*i], acc0[2*i+1]};
        G2BM(xp, b20, ok0, ok1);
        f32x2 xq = {acc1[2*i], acc1[2*i+1]};
        { f32x2 y_; PKADD(y_, xq, b21);
          y_[0] = ok0 ? y_[0] : 0.f; y_[1] = ok1 ? y_[1] : 0.f;
          f32x2 s_; PKFMA(s_, y_, y_, n1);
          f32x2 p_; PKFMA(p_, s_, K7, K6);
          PKFMA(p_, p_, s_, K5); PKFMA(p_, p_, s_, K4);
          PKFMA(p_, p_, s_, K3); PKFMA(p_, p_, s_, K2);
          PKFMA(p_, p_, s_, K1); PKFMA(p_, p_, s_, K0);
          PKADD(aX1, aX1, y_); PKADD(aP1, aP1, p_); }
      }
    }
  }
  float s0 = __builtin_fmaf(SQ2, aX[0]+aX[1], aP[0]+aP[1]);
  float s1v = __builtin_fmaf(SQ2, aX1[0]+aX1[1], aP1[0]+aP1[1]);
  s0 += __shfl_xor(s0, 32);
  s1v += __shfl_xor(s1v, 32);
  if (lane < 32){
    S[(size_t)g*1024 + 512 + col] = s0;
    S[(size_t)g*1024 + 512 + col + 32] = s1v;
  }
}

// ========== knode: 1 block/graph, 8 waves x 64 cols, K=48, pk-gelu ==========
__global__ __launch_bounds__(512) void knode(
    const unsigned short* __restrict__ nf48, const int* __restrict__ nstart,
    const unsigned short* __restrict__ w1n48T, const float* __restrict__ b1n_s,
    const float* __restrict__ pcoef, float* __restrict__ S){
  const int t = threadIdx.x;
  const int lane = t & 63, wid = t >> 6;
  const int hi = lane >> 5;
  const int g = blockIdx.x;
  const int col = (wid << 6) + (lane & 31);
  COEFS;
  const unsigned short* bp0 = w1n48T + col*48 + (hi<<3);
  const unsigned short* bp1 = w1n48T + (col+32)*48 + (hi<<3);
  short8 b00 = *(const short8*)(bp0), b01 = *(const short8*)(bp0+16), b02 = *(const short8*)(bp0+32);
  short8 b10 = *(const short8*)(bp1), b11 = *(const short8*)(bp1+16), b12 = *(const short8*)(bp1+32);
  float bv0 = b1n_s[col], bv1 = b1n_s[col+32];
  const f32x2 b20 = {bv0,bv0}, b21 = {bv1,bv1};
  f32x16 z16;
#pragma unroll
  for (int i=0;i<16;++i) z16[i] = 0.f;
  f32x2 aX = {0.f,0.f}, aP = {0.f,0.f};
  f32x2 aX1 = {0.f,0.f}, aP1 = {0.f,0.f};
  const int s0r = nstart[g], s1 = nstart[g+1];
  const int nch = (s1 - s0r + 31) >> 5;
  for (int ch=0; ch<nch; ++ch){
    const int rb = s0r + ch*32;
    int ar = min(rb + (lane & 31), s1-1);
    const unsigned short* apn = nf48 + (size_t)ar*48 + (hi<<3);
    short8 a0 = *(const short8*)(apn);
    short8 a1 = *(const short8*)(apn + 16);
    short8 a2 = *(const short8*)(apn + 32);
    f32x16 acc0 = __builtin_amdgcn_mfma_f32_32x32x16_bf16(a0, b00, z16, 0, 0, 0);
    acc0 = __builtin_amdgcn_mfma_f32_32x32x16_bf16(a1, b01, acc0, 0, 0, 0);
    acc0 = __builtin_amdgcn_mfma_f32_32x32x16_bf16(a2, b02, acc0, 0, 0, 0);
    f32x16 acc1 = __builtin_amdgcn_mfma_f32_32x32x16_bf16(a0, b10, z16, 0, 0, 0);
    acc1 = __builtin_amdgcn_mfma_f32_32x32x16_bf16(a1, b11, acc1, 0, 0, 0);
    acc1 = __builtin_amdgcn_mfma_f32_32x32x16_bf16(a2, b12, acc1, 0, 0, 0);
    const int vr = s1 - rb;
    if (vr >= 32){
#pragma unroll
      for (int i=0;i<8;++i){
        f32x2 xp = {acc0[2*i], acc0[2*i+1]};
        G2B(xp, b20);
      }
#pragma unroll
      for (int i=0;i<8;++i){
        f32x2 xp = {acc1[2*i], acc1[2*i+1]};
        { f32x2 y_; PKADD(y_, xp, b21);
          f32x2 s_; PKFMA(s_, y_, y_, n1);
          f32x2 p_; PKFMA(p_, s_, K7, K6);
          PKFMA(p_, p_, s_, K5); PKFMA(p_, p_, s_, K4);
          PKFMA(p_, p_, s_, K3); PKFMA(p_, p_, s_, K2);
          PKFMA(p_, p_, s_, K1); PKFMA(p_, p_, s_, K0);
          PKADD(aX1, aX1, y_); PKADD(aP1, aP1, p_); }
      }
    } else {
#pragma unroll
      for (int i=0;i<8;++i){
        int r0 = ((2*i)&3) + (((2*i)>>2)<<3) + (hi<<2);
        bool ok0 = r0 < vr, ok1 = (r0+1) < vr;
        f32x2 xp = {acc0[2*i], acc0[2*i+1]};
        G2BM(xp, b20, ok0, ok1);
        f32x2 xq = {acc1[2*i], acc1[2*i+1]};
        { f32x2 y_; PKADD(y_, xq, b21);
          y_[0] = ok0 ? y_[0] : 0.f; y_[1] = ok1 ? y_[1] : 0.f;
          f32x2 s_; PKFMA(s_, y_, y_, n1);
          f32x2 p_; PKFMA(p_, s_, K7, K6);
          PKFMA(p_, p_, s_, K5); PKFMA(p_, p_, s_, K4);
          PKFMA(p_, p_, s_, K3); PKFMA(p_, p_, s_, K2);
          PKFMA(p_, p_, s_, K1); PKFMA(p_, p_, s_, K0);
          PKADD(aX1, aX1, y_); PKADD(aP1, aP1, p_); }
      }
    }
  }
  float r0s = __builtin_fmaf(SQ2, aX[0]+aX[1], aP[0]+aP[1]);
  float r1s = __builtin_fmaf(SQ2, aX1[0]+aX1[1], aP1[0]+aP1[1]);
  r0s += __shfl_xor(r0s, 32);
  r1s += __shfl_xor(r1s, 32);
  if (lane < 32){
    S[(size_t)g*1024 + col] = r0s;
    S[(size_t)g*1024 + col + 32] = r1s;
  }
}

// ========== LDS-free bf16 split (hi+lo) MFMA GEMM (unchanged) ==========
__global__ __launch_bounds__(256) void kgemm3(const float* __restrict__ A, int lda, int nkc,
    const float* __restrict__ B0, const float* __restrict__ B1,
    float* __restrict__ out,
    const float* __restrict__ gf, const int* __restrict__ nstart, const int* __restrict__ cnt,
    const float* __restrict__ b2n, const float* __restrict__ b2e,
    const float* __restrict__ bias, const float* __restrict__ gam, const float* __restrict__ bet){
  const int t = threadIdx.x, lane = t & 63, w = t >> 6;
  const int q = lane >> 4, m = lane & 15;
  const int c0 = blockIdx.x*16, r0 = blockIdx.y*64 + w*16;
  f32x4 acc = {0.f,0.f,0.f,0.f};
  const float* ap = A + (size_t)(r0 + m)*lda + (q<<3);
  for (int kc = 0; kc < nkc; ++kc){
    const int ko = kc*32;
    float4 x = *(const float4*)(ap + ko);
    float4 y = *(const float4*)(ap + ko + 4);
    float v[8] = {x.x,x.y,x.z,x.w,y.x,y.y,y.z,y.w};
    short8 ah, al;
    split8(v, &ah, &al);
    const float* Bp = (kc < 16) ? B0 : B1;
    const float* bp = Bp + (size_t)((kc & 15)*32 + (q<<3))*HH + c0 + m;
    float bvv[8];
#pragma unroll
    for (int j=0;j<8;++j) bvv[j] = bp[(size_t)j*HH];
    short8 bh, bl;
    split8(bvv, &bh, &bl);
    acc = __builtin_amdgcn_mfma_f32_16x16x32_bf16(ah, bh, acc, 0, 0, 0);
    acc = __builtin_amdgcn_mfma_f32_16x16x32_bf16(ah, bl, acc, 0, 0, 0);
    acc = __builtin_amdgcn_mfma_f32_16x16x32_bf16(al, bh, acc, 0, 0, 0);
  }
  const float rs = 0.99999500003750f;
  const int c = c0 + m;
  if (gf){
    const float bnv = b2n[c], bev = b2e[c];
#pragma unroll
    for (int i=0;i<4;++i){
      int r = r0 + q*4 + i;
      float cn = (float)(nstart[r+1] - nstart[r]);
      float ce = (float)cnt[r];
      out[(size_t)r*HH + c] = acc[i] + gf[(size_t)r*HH + c] + cn*bnv + ce*bev;
    }
  } else {
    const float sc = gam[c]*rs, bi = bias[c], be = bet[c];
#pragma unroll
    for (int i=0;i<4;++i){
      int r = r0 + q*4 + i;
      out[(size_t)r*HH + c] = gelu_f((acc[i] + bi)*sc + be);
    }
  }
}

// ========== final 512 -> 2 linear (unchanged) ==========
__global__ __launch_bounds__(256) void kfinal(const float* __restrict__ x2, const float* __restrict__ w3,
    const float* __restrict__ b3, float* __restrict__ out){
  const int lane = threadIdx.x & 63, wv = threadIdx.x >> 6;
  const int r = blockIdx.x*4 + wv;
  float a0 = 0.f, a1 = 0.f;
#pragma unroll
  for (int tt=0; tt<8; ++tt){
    int k = lane + tt*64;
    float x = x2[(size_t)r*HH + k];
    a0 = __builtin_fmaf(x, w3[2*k], a0);
    a1 = __builtin_fmaf(x, w3[2*k+1], a1);
  }
#pragma unroll
  for (int d=1; d<64; d<<=1){ a0 += __shfl_xor(a0, d); a1 += __shfl_xor(a1, d); }
  if (lane == 0){ out[r*2] = a0 + b3[0]; out[r*2+1] = a1 + b3[1]; }
}

extern "C" void kernel_launch(void* const* d_in, const int* in_sizes, int n_in,
                              void* d_out, int out_size, void* d_ws, size_t ws_size,
                              hipStream_t stream) {
  const float* nf    = (const float*)d_in[0];
  const float* ef    = (const float*)d_in[1];
  const float* gf    = (const float*)d_in[2];
  const float* dp    = (const float*)d_in[3];
  const int*   ny    = (const int*)d_in[4];
  const int*   bidx  = (const int*)d_in[5];
  const int*   eidx  = (const int*)d_in[6];
  const float* nfw1  = (const float*)d_in[7];
  const float* nfb1  = (const float*)d_in[8];
  const float* nfg1  = (const float*)d_in[9];
  const float* nfbe1 = (const float*)d_in[10];
  const float* w2n   = (const float*)d_in[11];
  const float* b2n   = (const float*)d_in[12];
  const float* efw1  = (const float*)d_in[13];
  const float* efb1  = (const float*)d_in[14];
  const float* efg1  = (const float*)d_in[15];
  const float* efbe1 = (const float*)d_in[16];
  const float* w2e   = (const float*)d_in[17];
  const float* b2e   = (const float*)d_in[18];
  const float* ow1   = (const float*)d_in[19];
  const float* ob1   = (const float*)d_in[20];
  const float* og1   = (const float*)d_in[21];
  const float* obe1  = (const float*)d_in[22];
  const float* ow2   = (const float*)d_in[23];
  const float* ob2   = (const float*)d_in[24];
  const float* og2   = (const float*)d_in[25];
  const float* obe2  = (const float*)d_in[26];
  const float* ow3   = (const float*)d_in[27];
  const float* ob3   = (const float*)d_in[28];

  unsigned char* p = (unsigned char*)d_ws;
  float* S      = (float*)p;                 p += (size_t)NG*1024*4;  // 4MB
  int*   perm2d = (int*)p;                   p += (size_t)NG*ECAP*4;  // 4MB
  unsigned short* nf48 = (unsigned short*)p; p += (size_t)NN*48*2;    // 19.2MB (reused)
  unsigned short* efb  = (unsigned short*)p; p += (size_t)NE*16*2;    // 19.2MB
  unsigned short* w1n48T = (unsigned short*)p; p += 512*48*2;
  unsigned short* w1eT16 = (unsigned short*)p; p += 512*16*2;
  float* b1n_s  = (float*)p;                 p += 512*4;
  float* b1e_s  = (float*)p;                 p += 512*4;
  int* nstart   = (int*)p;                   p += 1032*4;
  int* cnt      = (int*)p;                   p += NG*4;
  float* pcoef  = (float*)p;                 p += 64;
  // eg aliases S (dead before kedge/knode write S)
  int* eg = (int*)S;
  // gh/xg2/x2f alias nf48 region (dead after knode)
  float* gh  = (float*)nf48;
  float* xg2 = gh  + (size_t)NG*HH;
  float* x2f = xg2 + (size_t)NG*HH;

  kpre<<<3913, 256, 0, stream>>>(nfw1, nfb1, nfg1, nfbe1, efw1, efb1, efg1, efbe1,
                                 w1n48T, w1eT16, b1n_s, b1e_s, bidx, nstart, cnt,
                                 pcoef, nf, dp, ny, ef, nf48, efb);
  kscatter<<<64, 1024, 0, stream>>>(eidx, bidx, eg, cnt, perm2d);
  kedge<<<NG, 512, 0, stream>>>(efb, perm2d, cnt, w1eT16, b1e_s, pcoef, S);
  knode<<<NG, 512, 0, stream>>>(nf48, nstart, w1n48T, b1n_s, pcoef, S);
  // G1: gh = S @ [w2n;w2e] + gf + cn*b2n + ce*b2e
  kgemm3<<<dim3(32,16), 256, 0, stream>>>(S, 1024, 32, w2n, w2e, gh,
                                          gf, nstart, cnt, b2n, b2e,
                                          nullptr, nullptr, nullptr);
  // G2: xg2 = gelu(bn(gh @ ow1 + ob1))
  kgemm3<<<dim3(32,16), 256, 0, stream>>>(gh, 512, 16, ow1, ow1, xg2,
                                          nullptr, nullptr, nullptr, nullptr, nullptr,
                                          ob1, og1, obe1);
  // G3: x2f = gelu(bn(xg2 @ ow2 + ob2))
  kgemm3<<<dim3(32,16), 256, 0, stream>>>(xg2, 512, 16, ow2, ow2, x2f,
                                          nullptr, nullptr, nullptr, nullptr, nullptr,
                                          ob2, og2, obe2);
  kfinal<<<NG/4, 256, 0, stream>>>(x2f, ow3, ob3, (float*)d_out);
}